// Round 7
// baseline (220.990 us; speedup 1.0000x reference)
//
#include <hip/hip_runtime.h>

// C = triu(A @ B), A,B upper-triangular fp32 4096x4096.
// R13: RAW BARRIER (no vmcnt drain). R12 post-mortem: 1-deep, 2-deep, and
// conflict-laden pipelines all have T_phase = 2.77us; m97's per-wg phase is
// the same 2.4us (it wins on 4 wg/CU). The invariant is the __syncthreads
// vmcnt(0) drain: hipcc emits s_waitcnt vmcnt(0) lgkmcnt(0) before s_barrier
// (m97 asm evidence), so register-load prefetch dies at every barrier and
// each phase pays full L3 latency. Fix (HK T4): replace __syncthreads with
//   s_waitcnt lgkmcnt(0)  (LDS visibility only - asm w/ memory clobber)
//   s_barrier             (raw builtin)
//   sched_barrier(0)      (rule #18: stop ds_reads hoisting above barrier)
// Register loads now survive the barrier; the compiler's dependence-driven
// vmcnt(16) at the consuming ds_write is the counted wait (T4). Everything
// else identical to R12 (even-cnp chunks keep buf0-start/buf1-end, so the
// chunk seam is race-free; lgkmcnt(0) retires cross-wave LDS ops).

#define N    4096
#define NB   32      // N / BM
#define BM   128
#define PK   64      // K per phase
#define NWG  512
#define CH   24      // max phases per chunk (even sizes enforced)
#define MAXF 832     // fragment capacity (actual: 774)
#define MAXL 64      // max per-wg load bound for LPT buckets

typedef __attribute__((ext_vector_type(8))) __bf16 bf16x8;
typedef __attribute__((ext_vector_type(4))) float  floatx4;
typedef __attribute__((ext_vector_type(8))) unsigned short ushort8;

// ---------------- compile-time split-K schedule (even fragment sizes) ------
struct Sched {
    unsigned short wgoff[NWG + 1];
    unsigned int   chunks[MAXF];   // bi|bj<<5|p0<<10|np<<17|atomic<<24
    int nf;
};

constexpr Sched make_sched() {
    Sched s{};
    unsigned int fr_sz[MAXF] = {};
    unsigned int fr_pk[MAXF] = {};
    int nf = 0;
    for (int d = NB - 1; d >= 0; --d) {
        const int npj  = 2 * (d + 1);                  // always even
        const int nc   = (npj + CH - 1) / CH;          // nc>1 iff d>=12
        const int base = (npj / nc) & ~1;              // even floor
        const int rem2 = (npj - nc * base) / 2;        // parts getting +2
        for (int bi = 0; bi + d < NB; ++bi) {
            const int bj = bi + d;
            int p0 = 0;
            for (int c = 0; c < nc; ++c) {
                const int fnp = base + (c < rem2 ? 2 : 0);   // even, >=2, <=CH
                fr_sz[nf] = (unsigned)fnp;
                fr_pk[nf] = (unsigned)bi | ((unsigned)bj << 5) |
                            ((unsigned)p0 << 10) | ((unsigned)fnp << 17) |
                            ((nc > 1 ? 1u : 0u) << 24);
                ++nf;
                p0 += fnp;
            }
        }
    }
    int order[MAXF] = {};
    int pos = 0;
    for (int sz = CH; sz >= 1; --sz)
        for (int i = 0; i < nf; ++i)
            if ((int)fr_sz[i] == sz) order[pos++] = i;
    int bcnt[MAXL] = {};
    int blist[MAXL][NWG] = {};
    for (int b = 0; b < NWG; ++b) blist[0][b] = NWG - 1 - b;
    bcnt[0] = NWG;
    int assign[MAXF] = {};
    int minload = 0;
    for (int k = 0; k < nf; ++k) {
        const int f = order[k];
        while (bcnt[minload] == 0) ++minload;
        const int b  = blist[minload][--bcnt[minload]];
        const int nl = minload + (int)fr_sz[f];
        blist[nl][bcnt[nl]++] = b;
        assign[f] = b;
    }
    int cnt[NWG] = {};
    for (int f = 0; f < nf; ++f) cnt[assign[f]]++;
    s.wgoff[0] = 0;
    for (int b = 0; b < NWG; ++b)
        s.wgoff[b + 1] = (unsigned short)(s.wgoff[b] + cnt[b]);
    int fill[NWG] = {};
    for (int f = 0; f < nf; ++f) {
        const int b = assign[f];
        s.chunks[s.wgoff[b] + fill[b]++] = fr_pk[f];
    }
    s.nf = nf;
    return s;
}

__device__ constexpr Sched g_sched = make_sched();

__device__ __forceinline__ unsigned short f32_to_bf16_rne(float f) {
    unsigned u = __builtin_bit_cast(unsigned, f);
    unsigned r = u + 0x7fffu + ((u >> 16) & 1u);
    return (unsigned short)(r >> 16);
}

// --- fused prep: A->bf16 (upper blocks), B->bf16 transposed (needed blocks),
//     zero C on strictly-lower 128-blocks AND split-K tiles (d>=12) ---
__global__ __launch_bounds__(256)
void prep_kernel(const float* __restrict__ A, const float* __restrict__ B,
                 unsigned short* __restrict__ Ab, unsigned short* __restrict__ Bt,
                 float* __restrict__ C) {
    __shared__ float tile[64][65];
    const int bx = blockIdx.x, by = blockIdx.y;      // 64-granule col/row
    const int x0 = bx * 64, y0 = by * 64;
    const int xb = bx >> 1, yb = by >> 1;            // 128-blocks
    const int t  = threadIdx.x;
    const int tr = t >> 2, tc = (t & 3) * 16;        // 64x(16/thread)

    if (xb >= yb) {
        const float* src = A + (size_t)(y0 + tr) * N + x0 + tc;
        const float4 v0 = ((const float4*)src)[0];
        const float4 v1 = ((const float4*)src)[1];
        const float4 v2 = ((const float4*)src)[2];
        const float4 v3 = ((const float4*)src)[3];
        ushort8 o0, o1;
        o0[0]=f32_to_bf16_rne(v0.x); o0[1]=f32_to_bf16_rne(v0.y);
        o0[2]=f32_to_bf16_rne(v0.z); o0[3]=f32_to_bf16_rne(v0.w);
        o0[4]=f32_to_bf16_rne(v1.x); o0[5]=f32_to_bf16_rne(v1.y);
        o0[6]=f32_to_bf16_rne(v1.z); o0[7]=f32_to_bf16_rne(v1.w);
        o1[0]=f32_to_bf16_rne(v2.x); o1[1]=f32_to_bf16_rne(v2.y);
        o1[2]=f32_to_bf16_rne(v2.z); o1[3]=f32_to_bf16_rne(v2.w);
        o1[4]=f32_to_bf16_rne(v3.x); o1[5]=f32_to_bf16_rne(v3.y);
        o1[6]=f32_to_bf16_rne(v3.z); o1[7]=f32_to_bf16_rne(v3.w);
        unsigned short* dst = Ab + (size_t)(y0 + tr) * N + x0 + tc;
        ((ushort8*)dst)[0] = o0;
        ((ushort8*)dst)[1] = o1;
    }
    if (xb <= yb) {
        const float* src = B + (size_t)(x0 + tr) * N + y0 + tc;   // B[k][j]
        const float4 v0 = ((const float4*)src)[0];
        const float4 v1 = ((const float4*)src)[1];
        const float4 v2 = ((const float4*)src)[2];
        const float4 v3 = ((const float4*)src)[3];
        float* d = &tile[tr][tc];
        d[0]=v0.x; d[1]=v0.y; d[2]=v0.z; d[3]=v0.w;
        d[4]=v1.x; d[5]=v1.y; d[6]=v1.z; d[7]=v1.w;
        d[8]=v2.x; d[9]=v2.y; d[10]=v2.z; d[11]=v2.w;
        d[12]=v3.x; d[13]=v3.y; d[14]=v3.z; d[15]=v3.w;
        __syncthreads();
        ushort8 o0, o1;
        #pragma unroll
        for (int i = 0; i < 8; ++i) o0[i] = f32_to_bf16_rne(tile[tc + i][tr]);
        #pragma unroll
        for (int i = 0; i < 8; ++i) o1[i] = f32_to_bf16_rne(tile[tc + 8 + i][tr]);
        unsigned short* dst = Bt + (size_t)(y0 + tr) * N + x0 + tc;
        ((ushort8*)dst)[0] = o0;
        ((ushort8*)dst)[1] = o1;
    }
    if (xb < yb || (xb - yb) >= 12) {
        float4 z = {0.f, 0.f, 0.f, 0.f};
        float* dst = C + (size_t)(y0 + tr) * N + x0 + tc;
        ((float4*)dst)[0] = z; ((float4*)dst)[1] = z;
        ((float4*)dst)[2] = z; ((float4*)dst)[3] = z;
    }
}

// ---- straight-line pipeline building blocks (all indices compile-time) ----

// Raw barrier: LDS visibility only (lgkmcnt), NO vmcnt drain -> register
// global loads stay in flight across it. sched_barrier stops the compiler
// hoisting the following ds_reads above s_barrier (rule #18).
#define BARRIER() {                                                           \
    asm volatile("s_waitcnt lgkmcnt(0)" ::: "memory");                        \
    __builtin_amdgcn_s_barrier();                                             \
    __builtin_amdgcn_sched_barrier(0);                                        \
}

#define STAGE(BUF, AB, BB) {                                                  \
    _Pragma("unroll")                                                         \
    for (int i = 0; i < 4; ++i) *(ushort8*)&sA[BUF][lwofs[i]] = AB[i];        \
    _Pragma("unroll")                                                         \
    for (int i = 0; i < 4; ++i) *(ushort8*)&sB[BUF][lwofs[i]] = BB[i];        \
}

#define LOADNEXT(AB, BB) {                                                    \
    _Pragma("unroll")                                                         \
    for (int i = 0; i < 4; ++i) { AB[i] = *(const ushort8*)gA[i]; gA[i] += PK; } \
    _Pragma("unroll")                                                         \
    for (int i = 0; i < 4; ++i) { BB[i] = *(const ushort8*)gB[i]; gB[i] += PK; } \
}

#define COMPUTE(BUF) {                                                        \
    _Pragma("unroll")                                                         \
    for (int h = 0; h < 2; ++h) {                                             \
        const int chh = h ? c1 : c0;                                          \
        bf16x8 af[4], bfr[4];                                                 \
        _Pragma("unroll")                                                     \
        for (int t = 0; t < 4; ++t) {                                         \
            af[t]  = *(const bf16x8*)&sA[BUF][(m0 + t * 16 + l15) * PK + chh];\
            bfr[t] = *(const bf16x8*)&sB[BUF][(n0 + t * 16 + l15) * PK + chh];\
        }                                                                     \
        _Pragma("unroll")                                                     \
        for (int tm = 0; tm < 4; ++tm)                                        \
            _Pragma("unroll")                                                 \
            for (int tn = 0; tn < 4; ++tn)                                    \
                acc[tm][tn] = __builtin_amdgcn_mfma_f32_16x16x32_bf16(        \
                    af[tm], bfr[tn], acc[tm][tn], 0, 0, 0);                   \
    }                                                                         \
}

// --- balanced split-K triangular MFMA GEMM, 2-deep reg-staged pipeline ---
__global__ __launch_bounds__(256, 2)
void trimm_kernel(const unsigned short* __restrict__ Ab,
                  const unsigned short* __restrict__ Bt,
                  float* __restrict__ C) {
    __shared__ unsigned short sA[2][BM * PK];   // 2 x 16 KiB, [128][64] swizzled
    __shared__ unsigned short sB[2][BM * PK];   // 2 x 16 KiB

    const int tid  = threadIdx.x;
    const int w    = tid >> 6;
    const int lane = tid & 63;
    const int quad = lane >> 4;
    const int l15  = lane & 15;

    const int m0 = (w >> 1) * 64;
    const int n0 = (w & 1) * 64;

    // staging: instr i covers rows w*32+i*8..+8; lane -> row +(lane>>3).
    // Global chunk LINEAR (coalesced); LDS write chunk XOR-swizzled:
    // LDS[r][q] = G[r][q ^ (r&7)]  (layout + 0-conflict verified R8-R12).
    const int srow = lane >> 3;
    const int qlin = (lane & 7) * 8;                       // linear global chunk
    int rr[4], lwofs[4];
    #pragma unroll
    for (int i = 0; i < 4; ++i) {
        rr[i]    = w * 32 + i * 8 + srow;
        lwofs[i] = rr[i] * PK + (((lane & 7) ^ srow) * 8); // swizzled LDS write
    }

    // read-side swizzle (verified R8-R12): e=row&7; chunk(h) = (h*4+quad)^e
    const int e  = l15 & 7;
    const int c0 = ((quad ^ (e & 3)) + 4 * (e >> 2)) * 8;        // h=0
    const int c1 = ((quad ^ (e & 3)) + 4 * (1 ^ (e >> 2))) * 8;  // h=1

    const int b  = (int)blockIdx.x;
    const int j0 = g_sched.wgoff[b];
    const int j1 = g_sched.wgoff[b + 1];

    for (int j = j0; j < j1; ++j) {
        const unsigned int ck = g_sched.chunks[j];
        const int bi   = ck & 31;
        const int bj   = (ck >> 5) & 31;
        const int p0   = (ck >> 10) & 127;
        const int cnp  = (ck >> 17) & 127;     // phases in this chunk (EVEN, >=2)
        const bool is_at = (ck >> 24) & 1u;

        const int row0 = bi * BM;
        const int col0 = bj * BM;
        const int k0   = bi * BM + p0 * PK;    // chunk K start

        floatx4 acc[4][4] = {};

        const unsigned short* gA[4];
        const unsigned short* gB[4];
        #pragma unroll
        for (int i = 0; i < 4; ++i) {
            gA[i] = Ab + (size_t)(row0 + rr[i]) * N + k0 + qlin;
            gB[i] = Bt + (size_t)(col0 + rr[i]) * N + k0 + qlin;
        }

        // 2-deep preload: phases 0 and 1 into the two named banks
        ushort8 a0[4], b0[4], a1[4], b1[4];
        LOADNEXT(a0, b0)
        LOADNEXT(a1, b1)

        // steady state: full pairs with prefetch of ph+2 / ph+3.
        // Per phase: STAGE bufX (compiler emits counted vmcnt for the
        // consumed bank - T4), issue next loads, raw BARRIER (lgkm only,
        // loads stay in flight), COMPUTE bufX. Buffers alternate; lgkmcnt(0)
        // before each barrier retires all waves' LDS reads+writes, so the
        // write(next)/read(cur) seam is safe with 1 barrier/phase.
        for (int ph = 0; ph + 2 < cnp; ph += 2) {
            STAGE(0, a0, b0)
            LOADNEXT(a0, b0)                  // phase ph+2, 2 phases of flight
            BARRIER()
            COMPUTE(0)
            STAGE(1, a1, b1)
            LOADNEXT(a1, b1)                  // phase ph+3
            BARRIER()
            COMPUTE(1)
        }
        // tail pair: no prefetch
        STAGE(0, a0, b0)
        BARRIER()
        COMPUTE(0)
        STAGE(1, a1, b1)
        BARRIER()
        COMPUTE(1)

        // epilogue. C/D layout: col=l15, row=quad*4+r
        #pragma unroll
        for (int tm = 0; tm < 4; ++tm) {
            const int grow_base = row0 + m0 + tm * 16 + quad * 4;
            #pragma unroll
            for (int tn = 0; tn < 4; ++tn) {
                const int gcol = col0 + n0 + tn * 16 + l15;
                #pragma unroll
                for (int r = 0; r < 4; ++r) {
                    const int grow = grow_base + r;
                    const float v = acc[tm][tn][r];
                    if (is_at) {
                        atomicAdd(&C[(size_t)grow * N + gcol], v);   // split tile
                    } else if (bi != bj) {
                        C[(size_t)grow * N + gcol] = v;              // single writer
                    } else {
                        C[(size_t)grow * N + gcol] = (gcol >= grow) ? v : 0.0f;
                    }
                }
            }
        }
    }
}

extern "C" void kernel_launch(void* const* d_in, const int* in_sizes, int n_in,
                              void* d_out, int out_size, void* d_ws, size_t ws_size,
                              hipStream_t stream) {
    const float* A = (const float*)d_in[0];
    const float* B = (const float*)d_in[1];
    float* C = (float*)d_out;

    unsigned short* Ab = (unsigned short*)d_ws;              // 32 MiB
    unsigned short* Bt = Ab + (size_t)N * N;                 // 32 MiB

    prep_kernel<<<dim3(N / 64, N / 64), dim3(256), 0, stream>>>(A, B, Ab, Bt, C);
    trimm_kernel<<<dim3(NWG), dim3(256), 0, stream>>>(Ab, Bt, C);
}

// Round 8
// 217.038 us; speedup vs baseline: 1.0182x; 1.0182x over previous
//
#include <hip/hip_runtime.h>

// C = triu(A @ B), A,B upper-triangular fp32 4096x4096.
// R14: OCCUPANCY 8 -> 16 waves/CU. R13 post-mortem: raw barrier changed
// nothing; 4 structurally different pipelines all sit at 2.77us/wg-slot.
// Ledger vs m97 (same tile, same per-phase FLOP): m97 = 12 waves/CU ->
// 1.63 phases/us/CU; ours = 8 waves/CU -> 0.72. TLP is the remaining lever
// (m114: co-resident waves overlap MFMA/VMEM/LDS pipes; 2 waves/SIMD is too
// thin). This round changes ONE variable: workgroup 256 -> 512 threads
// (8 waves, 2x4 grid, 64x32 sub-tile each, acc[4][2]); LDS/PK/schedule/
// pipeline identical to R13 (raw lgkm-only barrier, 2-deep reg prefetch,
// verified XOR swizzle). NWG=512 still all-resident at 2 wg/CU -> 16
// waves/CU. VGPR ~110 under launch_bounds(512,4) cap of 128.

#define N    4096
#define NB   32      // N / BM
#define BM   128
#define PK   64      // K per phase
#define NWG  512
#define CH   24      // max phases per chunk (even sizes enforced)
#define MAXF 832     // fragment capacity (actual: 774)
#define MAXL 64      // max per-wg load bound for LPT buckets

typedef __attribute__((ext_vector_type(8))) __bf16 bf16x8;
typedef __attribute__((ext_vector_type(4))) float  floatx4;
typedef __attribute__((ext_vector_type(8))) unsigned short ushort8;

// ---------------- compile-time split-K schedule (even fragment sizes) ------
struct Sched {
    unsigned short wgoff[NWG + 1];
    unsigned int   chunks[MAXF];   // bi|bj<<5|p0<<10|np<<17|atomic<<24
    int nf;
};

constexpr Sched make_sched() {
    Sched s{};
    unsigned int fr_sz[MAXF] = {};
    unsigned int fr_pk[MAXF] = {};
    int nf = 0;
    for (int d = NB - 1; d >= 0; --d) {
        const int npj  = 2 * (d + 1);                  // always even
        const int nc   = (npj + CH - 1) / CH;          // nc>1 iff d>=12
        const int base = (npj / nc) & ~1;              // even floor
        const int rem2 = (npj - nc * base) / 2;        // parts getting +2
        for (int bi = 0; bi + d < NB; ++bi) {
            const int bj = bi + d;
            int p0 = 0;
            for (int c = 0; c < nc; ++c) {
                const int fnp = base + (c < rem2 ? 2 : 0);   // even, >=2, <=CH
                fr_sz[nf] = (unsigned)fnp;
                fr_pk[nf] = (unsigned)bi | ((unsigned)bj << 5) |
                            ((unsigned)p0 << 10) | ((unsigned)fnp << 17) |
                            ((nc > 1 ? 1u : 0u) << 24);
                ++nf;
                p0 += fnp;
            }
        }
    }
    int order[MAXF] = {};
    int pos = 0;
    for (int sz = CH; sz >= 1; --sz)
        for (int i = 0; i < nf; ++i)
            if ((int)fr_sz[i] == sz) order[pos++] = i;
    int bcnt[MAXL] = {};
    int blist[MAXL][NWG] = {};
    for (int b = 0; b < NWG; ++b) blist[0][b] = NWG - 1 - b;
    bcnt[0] = NWG;
    int assign[MAXF] = {};
    int minload = 0;
    for (int k = 0; k < nf; ++k) {
        const int f = order[k];
        while (bcnt[minload] == 0) ++minload;
        const int b  = blist[minload][--bcnt[minload]];
        const int nl = minload + (int)fr_sz[f];
        blist[nl][bcnt[nl]++] = b;
        assign[f] = b;
    }
    int cnt[NWG] = {};
    for (int f = 0; f < nf; ++f) cnt[assign[f]]++;
    s.wgoff[0] = 0;
    for (int b = 0; b < NWG; ++b)
        s.wgoff[b + 1] = (unsigned short)(s.wgoff[b] + cnt[b]);
    int fill[NWG] = {};
    for (int f = 0; f < nf; ++f) {
        const int b = assign[f];
        s.chunks[s.wgoff[b] + fill[b]++] = fr_pk[f];
    }
    s.nf = nf;
    return s;
}

__device__ constexpr Sched g_sched = make_sched();

__device__ __forceinline__ unsigned short f32_to_bf16_rne(float f) {
    unsigned u = __builtin_bit_cast(unsigned, f);
    unsigned r = u + 0x7fffu + ((u >> 16) & 1u);
    return (unsigned short)(r >> 16);
}

// --- fused prep: A->bf16 (upper blocks), B->bf16 transposed (needed blocks),
//     zero C on strictly-lower 128-blocks AND split-K tiles (d>=12) ---
__global__ __launch_bounds__(256)
void prep_kernel(const float* __restrict__ A, const float* __restrict__ B,
                 unsigned short* __restrict__ Ab, unsigned short* __restrict__ Bt,
                 float* __restrict__ C) {
    __shared__ float tile[64][65];
    const int bx = blockIdx.x, by = blockIdx.y;      // 64-granule col/row
    const int x0 = bx * 64, y0 = by * 64;
    const int xb = bx >> 1, yb = by >> 1;            // 128-blocks
    const int t  = threadIdx.x;
    const int tr = t >> 2, tc = (t & 3) * 16;        // 64x(16/thread)

    if (xb >= yb) {
        const float* src = A + (size_t)(y0 + tr) * N + x0 + tc;
        const float4 v0 = ((const float4*)src)[0];
        const float4 v1 = ((const float4*)src)[1];
        const float4 v2 = ((const float4*)src)[2];
        const float4 v3 = ((const float4*)src)[3];
        ushort8 o0, o1;
        o0[0]=f32_to_bf16_rne(v0.x); o0[1]=f32_to_bf16_rne(v0.y);
        o0[2]=f32_to_bf16_rne(v0.z); o0[3]=f32_to_bf16_rne(v0.w);
        o0[4]=f32_to_bf16_rne(v1.x); o0[5]=f32_to_bf16_rne(v1.y);
        o0[6]=f32_to_bf16_rne(v1.z); o0[7]=f32_to_bf16_rne(v1.w);
        o1[0]=f32_to_bf16_rne(v2.x); o1[1]=f32_to_bf16_rne(v2.y);
        o1[2]=f32_to_bf16_rne(v2.z); o1[3]=f32_to_bf16_rne(v2.w);
        o1[4]=f32_to_bf16_rne(v3.x); o1[5]=f32_to_bf16_rne(v3.y);
        o1[6]=f32_to_bf16_rne(v3.z); o1[7]=f32_to_bf16_rne(v3.w);
        unsigned short* dst = Ab + (size_t)(y0 + tr) * N + x0 + tc;
        ((ushort8*)dst)[0] = o0;
        ((ushort8*)dst)[1] = o1;
    }
    if (xb <= yb) {
        const float* src = B + (size_t)(x0 + tr) * N + y0 + tc;   // B[k][j]
        const float4 v0 = ((const float4*)src)[0];
        const float4 v1 = ((const float4*)src)[1];
        const float4 v2 = ((const float4*)src)[2];
        const float4 v3 = ((const float4*)src)[3];
        float* d = &tile[tr][tc];
        d[0]=v0.x; d[1]=v0.y; d[2]=v0.z; d[3]=v0.w;
        d[4]=v1.x; d[5]=v1.y; d[6]=v1.z; d[7]=v1.w;
        d[8]=v2.x; d[9]=v2.y; d[10]=v2.z; d[11]=v2.w;
        d[12]=v3.x; d[13]=v3.y; d[14]=v3.z; d[15]=v3.w;
        __syncthreads();
        ushort8 o0, o1;
        #pragma unroll
        for (int i = 0; i < 8; ++i) o0[i] = f32_to_bf16_rne(tile[tc + i][tr]);
        #pragma unroll
        for (int i = 0; i < 8; ++i) o1[i] = f32_to_bf16_rne(tile[tc + 8 + i][tr]);
        unsigned short* dst = Bt + (size_t)(y0 + tr) * N + x0 + tc;
        ((ushort8*)dst)[0] = o0;
        ((ushort8*)dst)[1] = o1;
    }
    if (xb < yb || (xb - yb) >= 12) {
        float4 z = {0.f, 0.f, 0.f, 0.f};
        float* dst = C + (size_t)(y0 + tr) * N + x0 + tc;
        ((float4*)dst)[0] = z; ((float4*)dst)[1] = z;
        ((float4*)dst)[2] = z; ((float4*)dst)[3] = z;
    }
}

// ---- straight-line pipeline building blocks (all indices compile-time) ----

// Raw barrier: LDS visibility only (lgkmcnt), NO vmcnt drain -> register
// global loads stay in flight across it. sched_barrier stops the compiler
// hoisting the following ds_reads above s_barrier (rule #18).
#define BARRIER() {                                                           \
    asm volatile("s_waitcnt lgkmcnt(0)" ::: "memory");                        \
    __builtin_amdgcn_s_barrier();                                             \
    __builtin_amdgcn_sched_barrier(0);                                        \
}

#define STAGE(BUF, AB, BB) {                                                  \
    _Pragma("unroll")                                                         \
    for (int i = 0; i < 2; ++i) *(ushort8*)&sA[BUF][lwofs[i]] = AB[i];        \
    _Pragma("unroll")                                                         \
    for (int i = 0; i < 2; ++i) *(ushort8*)&sB[BUF][lwofs[i]] = BB[i];        \
}

#define LOADNEXT(AB, BB) {                                                    \
    _Pragma("unroll")                                                         \
    for (int i = 0; i < 2; ++i) { AB[i] = *(const ushort8*)gA[i]; gA[i] += PK; } \
    _Pragma("unroll")                                                         \
    for (int i = 0; i < 2; ++i) { BB[i] = *(const ushort8*)gB[i]; gB[i] += PK; } \
}

#define COMPUTE(BUF) {                                                        \
    _Pragma("unroll")                                                         \
    for (int h = 0; h < 2; ++h) {                                             \
        const int chh = h ? c1 : c0;                                          \
        bf16x8 af[4], bfr[2];                                                 \
        _Pragma("unroll")                                                     \
        for (int t = 0; t < 4; ++t)                                           \
            af[t]  = *(const bf16x8*)&sA[BUF][(m0 + t * 16 + l15) * PK + chh];\
        _Pragma("unroll")                                                     \
        for (int u = 0; u < 2; ++u)                                           \
            bfr[u] = *(const bf16x8*)&sB[BUF][(n0 + u * 16 + l15) * PK + chh];\
        _Pragma("unroll")                                                     \
        for (int tm = 0; tm < 4; ++tm)                                        \
            _Pragma("unroll")                                                 \
            for (int tn = 0; tn < 2; ++tn)                                    \
                acc[tm][tn] = __builtin_amdgcn_mfma_f32_16x16x32_bf16(        \
                    af[tm], bfr[tn], acc[tm][tn], 0, 0, 0);                   \
    }                                                                         \
}

// --- balanced split-K triangular MFMA GEMM, 8-wave wg, 2-deep pipeline ---
__global__ __launch_bounds__(512, 4)
void trimm_kernel(const unsigned short* __restrict__ Ab,
                  const unsigned short* __restrict__ Bt,
                  float* __restrict__ C) {
    __shared__ unsigned short sA[2][BM * PK];   // 2 x 16 KiB, [128][64] swizzled
    __shared__ unsigned short sB[2][BM * PK];   // 2 x 16 KiB

    const int tid  = threadIdx.x;
    const int w    = tid >> 6;        // 0..7
    const int lane = tid & 63;
    const int quad = lane >> 4;
    const int l15  = lane & 15;

    // 2x4 wave grid: each wave owns a 64x32 output sub-tile
    const int m0 = (w >> 2) * 64;     // wave-row * 64
    const int n0 = (w & 3) * 32;      // wave-col * 32

    // staging: wave w covers rows w*16 .. w*16+16; instr i in {0,1}:
    // rows w*16+i*8 + (lane>>3), 16B chunk lane&7.
    // Global chunk LINEAR (coalesced); LDS write chunk XOR-swizzled:
    // LDS[r][q] = G[r][q ^ (r&7)]  (layout + 0-conflict verified R8-R13).
    const int srow = lane >> 3;
    const int qlin = (lane & 7) * 8;                       // linear global chunk
    int rr[2], lwofs[2];
    #pragma unroll
    for (int i = 0; i < 2; ++i) {
        rr[i]    = w * 16 + i * 8 + srow;
        lwofs[i] = rr[i] * PK + (((lane & 7) ^ srow) * 8); // swizzled LDS write
    }

    // read-side swizzle (verified R8-R13): e=row&7; chunk(h) = (h*4+quad)^e
    const int e  = l15 & 7;
    const int c0 = ((quad ^ (e & 3)) + 4 * (e >> 2)) * 8;        // h=0
    const int c1 = ((quad ^ (e & 3)) + 4 * (1 ^ (e >> 2))) * 8;  // h=1

    const int b  = (int)blockIdx.x;
    const int j0 = g_sched.wgoff[b];
    const int j1 = g_sched.wgoff[b + 1];

    for (int j = j0; j < j1; ++j) {
        const unsigned int ck = g_sched.chunks[j];
        const int bi   = ck & 31;
        const int bj   = (ck >> 5) & 31;
        const int p0   = (ck >> 10) & 127;
        const int cnp  = (ck >> 17) & 127;     // phases in this chunk (EVEN, >=2)
        const bool is_at = (ck >> 24) & 1u;

        const int row0 = bi * BM;
        const int col0 = bj * BM;
        const int k0   = bi * BM + p0 * PK;    // chunk K start

        floatx4 acc[4][2] = {};

        const unsigned short* gA[2];
        const unsigned short* gB[2];
        #pragma unroll
        for (int i = 0; i < 2; ++i) {
            gA[i] = Ab + (size_t)(row0 + rr[i]) * N + k0 + qlin;
            gB[i] = Bt + (size_t)(col0 + rr[i]) * N + k0 + qlin;
        }

        // 2-deep preload: phases 0 and 1 into the two named banks
        ushort8 a0[2], b0[2], a1[2], b1[2];
        LOADNEXT(a0, b0)
        LOADNEXT(a1, b1)

        // steady state: full pairs with prefetch of ph+2 / ph+3.
        // 1 raw barrier per phase; buffers alternate; lgkmcnt(0) before each
        // barrier retires all waves' LDS ops -> seams race-free (R13 audit).
        for (int ph = 0; ph + 2 < cnp; ph += 2) {
            STAGE(0, a0, b0)
            LOADNEXT(a0, b0)                  // phase ph+2, 2 phases of flight
            BARRIER()
            COMPUTE(0)
            STAGE(1, a1, b1)
            LOADNEXT(a1, b1)                  // phase ph+3
            BARRIER()
            COMPUTE(1)
        }
        // tail pair: no prefetch
        STAGE(0, a0, b0)
        BARRIER()
        COMPUTE(0)
        STAGE(1, a1, b1)
        BARRIER()
        COMPUTE(1)

        // epilogue. C/D layout: col=l15, row=quad*4+r
        #pragma unroll
        for (int tm = 0; tm < 4; ++tm) {
            const int grow_base = row0 + m0 + tm * 16 + quad * 4;
            #pragma unroll
            for (int tn = 0; tn < 2; ++tn) {
                const int gcol = col0 + n0 + tn * 16 + l15;
                #pragma unroll
                for (int r = 0; r < 4; ++r) {
                    const int grow = grow_base + r;
                    const float v = acc[tm][tn][r];
                    if (is_at) {
                        atomicAdd(&C[(size_t)grow * N + gcol], v);   // split tile
                    } else if (bi != bj) {
                        C[(size_t)grow * N + gcol] = v;              // single writer
                    } else {
                        C[(size_t)grow * N + gcol] = (gcol >= grow) ? v : 0.0f;
                    }
                }
            }
        }
    }
}

extern "C" void kernel_launch(void* const* d_in, const int* in_sizes, int n_in,
                              void* d_out, int out_size, void* d_ws, size_t ws_size,
                              hipStream_t stream) {
    const float* A = (const float*)d_in[0];
    const float* B = (const float*)d_in[1];
    float* C = (float*)d_out;

    unsigned short* Ab = (unsigned short*)d_ws;              // 32 MiB
    unsigned short* Bt = Ab + (size_t)N * N;                 // 32 MiB

    prep_kernel<<<dim3(N / 64, N / 64), dim3(256), 0, stream>>>(A, B, Ab, Bt, C);
    trimm_kernel<<<dim3(NWG), dim3(512), 0, stream>>>(Ab, Bt, C);
}